// Round 1
// baseline (100.979 us; speedup 1.0000x reference)
//
#include <hip/hip_runtime.h>
#include <hip/hip_bf16.h>

#define IN_SIZE 65536
#define HIDDEN 128
#define D_STEPS 64
#define N_ACT 512
#define G4 (4 * HIDDEN)   // 512 gates

// ---------------- Kernel 1: ihx partials = split-K of w_ih @ x ----------------
// grid = 2048 blocks (512 rows x 4 column-chunks), 256 threads.
// Deterministic: partials[r*4+c] written by exactly one block; summed in k_rec.
__global__ __launch_bounds__(256) void k_ihx(const float* __restrict__ w_ih,
                                             const float* __restrict__ x,
                                             float* __restrict__ partials) {
    int bid = blockIdx.x;
    int r = bid >> 2;        // row 0..511
    int c = bid & 3;         // chunk 0..3 (16384 cols each)
    int t = threadIdx.x;
    const float4* wp = (const float4*)(w_ih + (size_t)r * IN_SIZE + c * 16384);
    const float4* xp = (const float4*)(x + c * 16384);
    float acc = 0.f;
#pragma unroll
    for (int i = 0; i < 16; ++i) {
        float4 w4 = wp[t + i * 256];
        float4 x4 = xp[t + i * 256];
        acc += w4.x * x4.x + w4.y * x4.y + w4.z * x4.z + w4.w * x4.w;
    }
    // wave(64) reduce
#pragma unroll
    for (int off = 32; off; off >>= 1) acc += __shfl_down(acc, off, 64);
    __shared__ float s[4];
    if ((t & 63) == 0) s[t >> 6] = acc;
    __syncthreads();
    if (t == 0) partials[r * 4 + c] = s[0] + s[1] + s[2] + s[3];
}

// ---------------- Kernel 2: sequential LSTM recurrence (1 block) ----------------
__device__ __forceinline__ float sigmoidf_(float v) { return 1.f / (1.f + __expf(-v)); }
__device__ __forceinline__ float tanhf_(float v)    { return 2.f / (1.f + __expf(-2.f * v)) - 1.f; }

__global__ __launch_bounds__(512, 2) void k_rec(const float* __restrict__ w_hh,
                                                const float* __restrict__ b_ih,
                                                const float* __restrict__ b_hh,
                                                const float* __restrict__ partials,
                                                float* __restrict__ h_hist) {
    int t = threadIdx.x;  // 0..511 : one gate row per thread
    // w_hh row t -> registers (128 VGPRs)
    float wr[HIDDEN];
    const float4* wp = (const float4*)(w_hh + (size_t)t * HIDDEN);
#pragma unroll
    for (int i = 0; i < HIDDEN / 4; ++i) {
        float4 v = wp[i];
        wr[4 * i + 0] = v.x; wr[4 * i + 1] = v.y;
        wr[4 * i + 2] = v.z; wr[4 * i + 3] = v.w;
    }
    float ihx = partials[t * 4 + 0] + partials[t * 4 + 1] +
                partials[t * 4 + 2] + partials[t * 4 + 3] +
                b_ih[t] + b_hh[t];

    __shared__ float h_s[HIDDEN];
    __shared__ float g_s[G4];
    float c = 0.f;  // cell state, threads 0..127
    if (t < HIDDEN) h_s[t] = 0.f;
    __syncthreads();

    for (int d = 0; d < D_STEPS; ++d) {
        float acc = ihx;
#pragma unroll
        for (int k = 0; k < HIDDEN; ++k) acc += wr[k] * h_s[k];  // h_s broadcast
        g_s[t] = acc;
        __syncthreads();
        if (t < HIDDEN) {
            float ig = sigmoidf_(g_s[t]);
            float fg = sigmoidf_(g_s[t + 128]);
            float gg = tanhf_(g_s[t + 256]);
            float og = sigmoidf_(g_s[t + 384]);
            c = fg * c + ig * gg;
            float h = og * tanhf_(c);
            h_s[t] = h;
            h_hist[d * HIDDEN + t] = h;
        }
        __syncthreads();
    }
}

// ---------------- Kernel 3: logits = w_lin @ h_d + b_lin for all d ----------------
// grid = 64 (one block per step), 512 threads (one per output row).
__global__ __launch_bounds__(512) void k_logits(const float* __restrict__ w_lin,
                                                const float* __restrict__ b_lin,
                                                const float* __restrict__ h_hist,
                                                float* __restrict__ out) {
    int d = blockIdx.x;
    int n = threadIdx.x;
    __shared__ float h_s[HIDDEN];
    if (n < HIDDEN) h_s[n] = h_hist[d * HIDDEN + n];
    __syncthreads();
    const float4* wp = (const float4*)(w_lin + (size_t)n * HIDDEN);
    float acc = b_lin[n];
#pragma unroll
    for (int k4 = 0; k4 < HIDDEN / 4; ++k4) {
        float4 w4 = wp[k4];
        acc += w4.x * h_s[4 * k4 + 0] + w4.y * h_s[4 * k4 + 1] +
               w4.z * h_s[4 * k4 + 2] + w4.w * h_s[4 * k4 + 3];
    }
    out[d * N_ACT + n] = acc;
}

extern "C" void kernel_launch(void* const* d_in, const int* in_sizes, int n_in,
                              void* d_out, int out_size, void* d_ws, size_t ws_size,
                              hipStream_t stream) {
    const float* x     = (const float*)d_in[0];
    const float* w_ih  = (const float*)d_in[1];
    const float* w_hh  = (const float*)d_in[2];
    const float* b_ih  = (const float*)d_in[3];
    const float* b_hh  = (const float*)d_in[4];
    const float* w_lin = (const float*)d_in[5];
    const float* b_lin = (const float*)d_in[6];
    float* out = (float*)d_out;

    float* ws       = (float*)d_ws;
    float* partials = ws;                  // 2048 floats
    float* h_hist   = ws + 2048;           // 8192 floats

    k_ihx<<<2048, 256, 0, stream>>>(w_ih, x, partials);
    k_rec<<<1, 512, 0, stream>>>(w_hh, b_ih, b_hh, partials, h_hist);
    k_logits<<<64, 512, 0, stream>>>(w_lin, b_lin, h_hist, out);
}

// Round 2
// 83.668 us; speedup vs baseline: 1.2069x; 1.2069x over previous
//
#include <hip/hip_runtime.h>
#include <hip/hip_bf16.h>

#define IN_SIZE 65536
#define HIDDEN 128
#define D_STEPS 64
#define N_ACT 512

typedef _Float16 half2_ __attribute__((ext_vector_type(2)));

__device__ __forceinline__ float dot2f(half2_ a, half2_ b, float c) {
#if __has_builtin(__builtin_amdgcn_fdot2)
    return __builtin_amdgcn_fdot2(a, b, c, false);
#else
    return c + (float)a[0] * (float)b[0] + (float)a[1] * (float)b[1];
#endif
}

// ---------------- Kernel 1: ihx partials = split-K of w_ih @ x ----------------
// grid = 2048 blocks (512 rows x 4 column-chunks), 256 threads. HBM-bound (134 MB).
__global__ __launch_bounds__(256) void k_ihx(const float* __restrict__ w_ih,
                                             const float* __restrict__ x,
                                             float* __restrict__ partials) {
    int bid = blockIdx.x;
    int r = bid >> 2;        // row 0..511
    int c = bid & 3;         // chunk 0..3 (16384 cols each)
    int t = threadIdx.x;
    const float4* wp = (const float4*)(w_ih + (size_t)r * IN_SIZE + c * 16384);
    const float4* xp = (const float4*)(x + c * 16384);
    float acc = 0.f;
#pragma unroll
    for (int i = 0; i < 16; ++i) {
        float4 w4 = wp[t + i * 256];
        float4 x4 = xp[t + i * 256];
        acc += w4.x * x4.x + w4.y * x4.y + w4.z * x4.z + w4.w * x4.w;
    }
#pragma unroll
    for (int off = 32; off; off >>= 1) acc += __shfl_down(acc, off, 64);
    __shared__ float s[4];
    if ((t & 63) == 0) s[t >> 6] = acc;
    __syncthreads();
    if (t == 0) partials[r * 4 + c] = s[0] + s[1] + s[2] + s[3];
}

// ---------------- Kernel 2: sequential LSTM recurrence (1 block, 512 threads) ----
// Thread t owns gate row (t&3)*128 + (t>>2): all 4 gates of cell j=t>>2 live in
// adjacent lanes 4j..4j+3 of ONE wave -> gate exchange via in-wave shuffles,
// activations computed redundantly by all lanes, ONE barrier per step
// (double-buffered h). Recurrent matvec in packed f16 via v_dot2_f32_f16.
__global__ __launch_bounds__(512) void k_rec(const float* __restrict__ w_hh,
                                             const float* __restrict__ b_ih,
                                             const float* __restrict__ b_hh,
                                             const float* __restrict__ partials,
                                             float* __restrict__ h_hist) {
    int t = threadIdx.x;            // 0..511
    int l = t & 63;                 // lane
    int gate = t & 3;               // 0:i 1:f 2:g 3:o
    int cell = t >> 2;              // 0..127
    int row = gate * HIDDEN + cell; // row in 4H gate layout

    // w_hh row -> 64 packed-f16 VGPRs
    half2_ wr[HIDDEN / 2];
    const float2* wp = (const float2*)(w_hh + (size_t)row * HIDDEN);
#pragma unroll
    for (int i = 0; i < HIDDEN / 2; ++i) {
        float2 v = wp[i];
        half2_ w2 = {(_Float16)v.x, (_Float16)v.y};
        wr[i] = w2;
    }
    float ihx = partials[row * 4 + 0] + partials[row * 4 + 1] +
                partials[row * 4 + 2] + partials[row * 4 + 3] +
                b_ih[row] + b_hh[row];

    __shared__ half2_ h_s[2][HIDDEN / 2];   // double buffer: 1 barrier/step
    float c = 0.f;                          // replicated 4x per cell (identical)
    if (t < HIDDEN / 2) { half2_ z = {(_Float16)0.f, (_Float16)0.f}; h_s[0][t] = z; }
    __syncthreads();

    for (int d = 0; d < D_STEPS; ++d) {
        int rb = d & 1, wb = rb ^ 1;
        const half2_* hb = h_s[rb];
        float a0 = 0.f, a1 = 0.f, a2 = 0.f, a3 = 0.f;
#pragma unroll
        for (int i = 0; i < HIDDEN / 2; i += 4) {   // broadcast LDS reads
            a0 = dot2f(wr[i + 0], hb[i + 0], a0);
            a1 = dot2f(wr[i + 1], hb[i + 1], a1);
            a2 = dot2f(wr[i + 2], hb[i + 2], a2);
            a3 = dot2f(wr[i + 3], hb[i + 3], a3);
        }
        float g = ihx + ((a0 + a1) + (a2 + a3));
        // own-gate activation: sigmoid for i,f,o ; tanh for g (tanh(x)=2*sig(2x)-1)
        float kmul = (gate == 2) ? 2.f : 1.f;
        float s = 1.f / (1.f + __expf(-kmul * g));
        float act = (gate == 2) ? (2.f * s - 1.f) : s;
        int base = l & ~3;
        float ai = __shfl(act, base + 0, 64);
        float af = __shfl(act, base + 1, 64);
        float at = __shfl(act, base + 2, 64);
        float ao = __shfl(act, base + 3, 64);
        c = af * c + ai * at;
        float h = ao * (2.f / (1.f + __expf(-2.f * c)) - 1.f);
        // pack h pairs: cells (2m,2m+1) -> lanes l and l+4 (gate-0 lanes)
        float hp = __shfl(h, (l + 4) & 63, 64);
        if ((t & 7) == 0) { half2_ p = {(_Float16)h, (_Float16)hp}; h_s[wb][t >> 3] = p; }
        if ((t & 3) == 0) h_hist[d * HIDDEN + cell] = h;
        __syncthreads();
    }
}

// ---------------- Kernel 3: logits = w_lin @ h_d + b_lin for all d ----------------
__global__ __launch_bounds__(512) void k_logits(const float* __restrict__ w_lin,
                                                const float* __restrict__ b_lin,
                                                const float* __restrict__ h_hist,
                                                float* __restrict__ out) {
    int d = blockIdx.x;
    int n = threadIdx.x;
    __shared__ float h_s[HIDDEN];
    if (n < HIDDEN) h_s[n] = h_hist[d * HIDDEN + n];
    __syncthreads();
    const float4* wp = (const float4*)(w_lin + (size_t)n * HIDDEN);
    float acc = b_lin[n];
#pragma unroll
    for (int k4 = 0; k4 < HIDDEN / 4; ++k4) {
        float4 w4 = wp[k4];
        acc += w4.x * h_s[4 * k4 + 0] + w4.y * h_s[4 * k4 + 1] +
               w4.z * h_s[4 * k4 + 2] + w4.w * h_s[4 * k4 + 3];
    }
    out[d * N_ACT + n] = acc;
}

extern "C" void kernel_launch(void* const* d_in, const int* in_sizes, int n_in,
                              void* d_out, int out_size, void* d_ws, size_t ws_size,
                              hipStream_t stream) {
    const float* x     = (const float*)d_in[0];
    const float* w_ih  = (const float*)d_in[1];
    const float* w_hh  = (const float*)d_in[2];
    const float* b_ih  = (const float*)d_in[3];
    const float* b_hh  = (const float*)d_in[4];
    const float* w_lin = (const float*)d_in[5];
    const float* b_lin = (const float*)d_in[6];
    float* out = (float*)d_out;

    float* ws       = (float*)d_ws;
    float* partials = ws;                  // 2048 floats
    float* h_hist   = ws + 2048;           // 8192 floats

    k_ihx<<<2048, 256, 0, stream>>>(w_ih, x, partials);
    k_rec<<<1, 512, 0, stream>>>(w_hh, b_ih, b_hh, partials, h_hist);
    k_logits<<<64, 512, 0, stream>>>(w_lin, b_lin, h_hist, out);
}